// Round 1
// baseline (248.968 us; speedup 1.0000x reference)
//
#include <hip/hip_runtime.h>
#include <hip/hip_bf16.h>
#include <cmath>

// R1: (a) finalize_ev eliminated -- per-(dst,rel) degree recomputed in-agg via
//     ballot histogram; weight via __shfl; padding via slot<cnt mask.
//     (b) memset folded into pack_bt. (c) gemm B-tiles: double-buffered LDS via
//     global_load_lds(16B) + XOR granule swizzle, 1 barrier/tile (T3 2-phase).
//     (d) scatter: 4 edges/thread, loads batched before atomics.

#define IN_DIM 128
#define HID 64
#define OUT_DIM 40
#define NREL 8
#define NCOLS 576   // 8*64 (relations) + 64 (root)
#define CAP 64      // max in-degree bucket capacity
#define CSTR 16     // cursor stride (ints) = one 64B line per dst

typedef __attribute__((ext_vector_type(8))) short short8;
typedef __attribute__((ext_vector_type(4))) short short4v;
typedef __attribute__((ext_vector_type(4))) float floatx4;
typedef __attribute__((ext_vector_type(2))) float f32x2;

static __device__ __forceinline__ short f2bf(float f) {
  __hip_bfloat16 h = __float2bfloat16(f);
  return __builtin_bit_cast(short, h);
}
static __device__ __forceinline__ float bflo(unsigned int u) {
  return __int_as_float(u << 16);
}
static __device__ __forceinline__ float bfhi(unsigned int u) {
  return __int_as_float(u & 0xffff0000u);
}
static __device__ __forceinline__ unsigned int packbf(float x, float y) {
  unsigned int lo = (unsigned short)f2bf(x);
  unsigned int hi = (unsigned short)f2bf(y);
  return lo | (hi << 16);
}

static __device__ __forceinline__ void gload_lds16(const void* g, void* l) {
  __builtin_amdgcn_global_load_lds(
      (const __attribute__((address_space(1))) unsigned int*)g,
      (__attribute__((address_space(3))) unsigned int*)l, 16, 0, 0);
}

// ---- pack Bt1, Bt2 + zero cursor (memset folded in) ------------------------
__global__ void pack_bt(const float* __restrict__ W1, const float* __restrict__ root1,
                        short* __restrict__ Bt1,
                        const float* __restrict__ W2, const float* __restrict__ root2,
                        short* __restrict__ Bt2,
                        int* __restrict__ cursor, int nzero4) {
  const int PB1 = (NCOLS * IN_DIM + 255) / 256;   // 288
  const int PB2 = (NCOLS * HID + 255) / 256;      // 144
  int b = blockIdx.x;
  if (b < PB1) {
    int i = b * 256 + threadIdx.x;
    if (i >= NCOLS * IN_DIM) return;
    int c = i / IN_DIM, k = i % IN_DIM;
    float v = (c < NREL * HID)
      ? W1[((size_t)(c >> 6) * IN_DIM + k) * HID + (c & 63)]
      : root1[(size_t)k * HID + (c - NREL * HID)];
    Bt1[i] = f2bf(v);
  } else if (b < PB1 + PB2) {
    int i = (b - PB1) * 256 + threadIdx.x;
    if (i >= NCOLS * HID) return;
    int c = i / HID, k = i % HID;
    float v = (c < NREL * HID)
      ? W2[((size_t)(c >> 6) * HID + k) * HID + (c & 63)]
      : root2[(size_t)k * HID + (c - NREL * HID)];
    Bt2[i] = f2bf(v);
  } else {
    int i = (b - PB1 - PB2) * 256 + threadIdx.x;
    if (i < nzero4) {
      int4 z; z.x = 0; z.y = 0; z.z = 0; z.w = 0;
      ((int4*)cursor)[i] = z;
    }
  }
}

// ---- B tile staging: global -> LDS DMA, XOR-swizzled source ----------------
// LDS slot (row, g) holds global granule (row, g ^ (row&7)); reader applies
// the same XOR. 16B granules; GR = K/8 granules per 64-col row.
template<int K>
static __device__ __forceinline__ void stage_b_tile(
    const short* __restrict__ tb, short* bufp, int wv, int lane) {
  constexpr int GR = K / 8;
  constexpr int CALLS = GR / 4;   // per wave: K=128 -> 4, K=64 -> 2
  #pragma unroll
  for (int j = 0; j < CALLS; ++j) {
    int c = wv * CALLS + j;          // wave-uniform
    int s = c * 64 + lane;           // granule id in tile
    int row = s / GR, g = s % GR;
    gload_lds16(tb + (row * GR + (g ^ (row & 7))) * 8, bufp + c * 512);
  }
}

// ---- shared MFMA GEMM body: C[64 x 576] = act(A tile) @ Bt^T ---------------
// Bs double-buffered (2 x 64*K shorts, unpadded+swizzled); 1 barrier/tile.
// AMODE 0: A fp32, no relu.  AMODE 1: A bf16, relu.
// cols 0..511 -> H (bf16); cols 512..575 -> AGG (bf16, +bias)
template<int K, int AMODE>
__device__ __forceinline__ void gemm_dev(
    short* As, short* Bs,
    const void* __restrict__ Aptr, const short* __restrict__ Bt,
    const float* __restrict__ bias, short* __restrict__ H,
    unsigned short* __restrict__ AGG, int M, int row0)
{
  constexpr int ASTA = K + 8;
  int tid = threadIdx.x;
  int wv = tid >> 6, lane = tid & 63;
  int lm = lane & 15, quad = lane >> 4;

  // issue DMA for B tile 0 into buffer 0 (latency hidden under A staging)
  stage_b_tile<K>(Bt, Bs, wv, lane);

  if (AMODE == 0) {
    const float* A = (const float*)Aptr;
    constexpr int CH = K / 4;
    for (int i = tid; i < 64 * CH; i += 256) {
      int r = i / CH, kq = i % CH;
      int gr = row0 + r; if (gr >= M) gr = M - 1;
      float4 v = *(const float4*)(A + (unsigned)(gr * K + kq * 4));
      short4v s;
      s.x = f2bf(v.x); s.y = f2bf(v.y); s.z = f2bf(v.z); s.w = f2bf(v.w);
      *(short4v*)(As + r * ASTA + kq * 4) = s;
    }
  } else {
    const short* A = (const short*)Aptr;
    constexpr int CH = K / 8;
    for (int i = tid; i < 64 * CH; i += 256) {
      int r = i / CH, ko = i % CH;
      int gr = row0 + r; if (gr >= M) gr = M - 1;
      short8 v = *(const short8*)(A + (unsigned)(gr * K + ko * 8));
      #pragma unroll
      for (int j = 0; j < 8; ++j)
        if ((unsigned short)v[j] & 0x8000u) v[j] = 0;   // bf16 relu
      *(short8*)(As + r * ASTA + ko * 8) = v;
    }
  }

  __syncthreads();   // A staged + tile0 DMA drained (vmcnt0 at barrier)

  const short* ap = As + (16 * wv + lm) * ASTA + quad * 8;
  const int swz = lm & 7;

  for (int cy = 0; cy < 9; ++cy) {
    const short* buf = Bs + (cy & 1) * (64 * K);
    if (cy < 8)   // prefetch next tile into other buffer; drains at barrier below
      stage_b_tile<K>(Bt + (cy + 1) * (64 * K), Bs + ((cy + 1) & 1) * (64 * K), wv, lane);

    floatx4 acc[4] = {{0,0,0,0},{0,0,0,0},{0,0,0,0},{0,0,0,0}};
    #pragma unroll
    for (int ks = 0; ks < K / 32; ++ks) {
      short8 a = *(const short8*)(ap + ks * 32);
      #pragma unroll
      for (int nb = 0; nb < 4; ++nb) {
        short8 b = *(const short8*)(buf + (nb * 16 + lm) * K +
                                    (((ks * 4 + quad) ^ swz) * 8));
        acc[nb] = __builtin_amdgcn_mfma_f32_16x16x32_bf16(a, b, acc[nb], 0, 0, 0);
      }
    }

    int mbase = row0 + 16 * wv + quad * 4;
    if (cy < 8) {
      #pragma unroll
      for (int nb = 0; nb < 4; ++nb) {
        int col = cy * 64 + nb * 16 + lm;
        #pragma unroll
        for (int r = 0; r < 4; ++r) {
          int mg = mbase + r;
          if (mg < M) H[(unsigned)mg * (NREL * HID) + col] = f2bf(acc[nb][r]);
        }
      }
    } else {
      #pragma unroll
      for (int nb = 0; nb < 4; ++nb) {
        int col = nb * 16 + lm;
        float bv = bias[col];
        #pragma unroll
        for (int r = 0; r < 4; ++r) {
          int mg = mbase + r;
          if (mg < M)
            AGG[(unsigned)mg * HID + col] = (unsigned short)f2bf(acc[nb][r] + bv);
        }
      }
    }
    if (cy < 8) __syncthreads();
  }
}

// ---- fused: gemm layer-1 (blocks < GB) + bucket scatter (blocks >= GB) -----
__global__ __launch_bounds__(256, 4) void gemm1_scatter(
    const float* __restrict__ A, const short* __restrict__ Bt,
    const float* __restrict__ bias, short* __restrict__ H,
    unsigned short* __restrict__ AGG, int M, int GB,
    const int* __restrict__ src, const int* __restrict__ dst,
    const int* __restrict__ et,
    int* __restrict__ cursor, int* __restrict__ ev, int E)
{
  __shared__ short As[64 * (IN_DIM + 8)];
  __shared__ short Bs[2 * 64 * IN_DIM];
  if ((int)blockIdx.x < GB) {
    gemm_dev<IN_DIM, 0>(As, Bs, A, Bt, bias, H, AGG, M, blockIdx.x * 64);
  } else {
    int base = (blockIdx.x - GB) * 1024 + threadIdx.x;
    int dd[4], ss[4], tt[4];
    #pragma unroll
    for (int u = 0; u < 4; ++u) {
      int e = base + u * 256;
      int ec = (e < E) ? e : 0;
      dd[u] = dst[ec]; ss[u] = src[ec]; tt[u] = et[ec];
    }
    #pragma unroll
    for (int u = 0; u < 4; ++u) {
      int e = base + u * 256;
      if (e < E) {
        int pos = atomicAdd(&cursor[dd[u] * CSTR], 1);
        if (pos < CAP) ev[dd[u] * CAP + pos] = (ss[u] << 3) | tt[u];
      }
    }
  }
}

// ---- gemm layer 2 (bf16 A with relu) ---------------------------------------
__global__ __launch_bounds__(256, 4) void gemm2_mfma(
    const unsigned short* __restrict__ A, const short* __restrict__ Bt,
    const float* __restrict__ bias, short* __restrict__ H,
    unsigned short* __restrict__ AGG, int M)
{
  __shared__ short As[64 * (HID + 8)];
  __shared__ short Bs[2 * 64 * HID];
  gemm_dev<HID, 1>(As, Bs, A, Bt, bias, H, AGG, M, blockIdx.x * 64);
}

// ---- fast aggregation core: HALF-WAVE per dst, raw ev ----------------------
// Entry v (raw) = (src<<3)|rel = H row index. wreg: lane (h*32+r) carries the
// weight 1/deg(dst,r) (replicated at lhl&7==r). Slots >= cnt masked.
static __device__ __forceinline__ void agg_half2(
    const uint2* __restrict__ Hu2, const int* __restrict__ evrow,
    int cnt, int qloc, int sub, float wreg, int h,
    float& a0, float& a1, float& a2, float& a3)
{
  int npass = (cnt + 15) >> 4;
  f32x2 A01 = {a0, a1}, A23 = {a2, a3};
  for (int P = 0; P < npass; ++P) {
    const int4* pp = (const int4*)(evrow + P * 16 + qloc * 8);
    int4 v0 = pp[0], v1 = pp[1];
    int vv[8] = {v0.x, v0.y, v0.z, v0.w, v1.x, v1.y, v1.z, v1.w};
    int sb = P * 16 + qloc * 8;
    uint2 hv[8];
    float ww[8];
    #pragma unroll
    for (int i = 0; i < 8; ++i) {
      bool ok = (sb + i) < cnt;
      int v = ok ? vv[i] : 0;            // clamp garbage padding slots
      hv[i] = Hu2[(unsigned)v * 16u + (unsigned)sub];
      float w = __shfl(wreg, h * 32 + (v & 7), 64);
      ww[i] = ok ? w : 0.f;
    }
    #pragma unroll
    for (int i = 0; i < 8; ++i) {
      f32x2 w2 = {ww[i], ww[i]};
      f32x2 h01 = {bflo(hv[i].x), bfhi(hv[i].x)};
      f32x2 h23 = {bflo(hv[i].y), bfhi(hv[i].y)};
      A01 += h01 * w2;
      A23 += h23 * w2;
    }
  }
  a0 = A01.x; a1 = A01.y; a2 = A23.x; a3 = A23.y;
  a0 += __shfl_xor(a0, 16, 64);
  a1 += __shfl_xor(a1, 16, 64);
  a2 += __shfl_xor(a2, 16, 64);
  a3 += __shfl_xor(a3, 16, 64);
}

// ballot histogram: per-lane weight 1/deg(dst, lhl&7) for this half's dst
static __device__ __forceinline__ float rel_weight(
    const int* __restrict__ evr, int cnt, int lhl, int h)
{
  int e0 = evr[lhl], e1 = evr[lhl + 32];
  bool v0 = lhl < cnt, v1 = (lhl + 32) < cnt;
  int r0 = e0 & 7, r1 = e1 & 7;
  unsigned long long hm = 0xffffffffull << (h * 32);
  int myrel = lhl & 7;
  int c = 0;
  #pragma unroll
  for (int r = 0; r < 8; ++r) {
    unsigned long long m0 = __ballot(v0 && (r0 == r));
    unsigned long long m1 = __ballot(v1 && (r1 == r));
    int cr = __popcll(m0 & hm) + __popcll(m1 & hm);
    if (myrel == r) c = cr;
  }
  return (c > 0) ? (1.0f / (float)c) : 0.0f;
}

// ---- layer-1 aggregation: 2 dsts per wave, AGG(bf16) += mean-messages ------
__global__ __launch_bounds__(256) void csr_agg(
    const short* __restrict__ H, const int* __restrict__ cursor,
    const int* __restrict__ ev, unsigned short* __restrict__ AGG, int N)
{
  int tid = threadIdx.x;
  int wv = tid >> 6, lane = tid & 63;
  int h = lane >> 5, lhl = lane & 31, qloc = lhl >> 4, sub = lhl & 15;
  int d = blockIdx.x * 8 + wv * 2 + h;
  int dc = d < N ? d : N - 1;

  int cnt = cursor[dc * CSTR]; if (cnt > CAP) cnt = CAP;
  const int* evr = ev + dc * CAP;
  float wreg = rel_weight(evr, cnt, lhl, h);

  float a0 = 0.f, a1 = 0.f, a2 = 0.f, a3 = 0.f;
  uint2* aggrow = (uint2*)(AGG + (size_t)dc * HID);
  if (qloc == 0) {
    uint2 iv = aggrow[sub];
    a0 = bflo(iv.x); a1 = bfhi(iv.x); a2 = bflo(iv.y); a3 = bfhi(iv.y);
  }
  agg_half2((const uint2*)H, evr, cnt, qloc, sub, wreg, h, a0, a1, a2, a3);
  if (d < N && qloc == 0) {
    uint2 ov;
    ov.x = packbf(a0, a1);
    ov.y = packbf(a2, a3);
    aggrow[sub] = ov;
  }
}

// ---- layer-2 aggregation (2 dsts/wave) + relu -> @Wl+bl -> log_softmax -----
__global__ __launch_bounds__(256) void csr_agg_final(
    const short* __restrict__ H, const int* __restrict__ cursor,
    const int* __restrict__ ev, const unsigned short* __restrict__ AGG,
    const float* __restrict__ Wl, const float* __restrict__ bl,
    float* __restrict__ out, int N)
{
  __shared__ float sWl[HID * OUT_DIM];
  __shared__ float sbl[OUT_DIM];
  __shared__ float sh[8][HID];
  int tid = threadIdx.x;
  int wv = tid >> 6, lane = tid & 63;
  int h = lane >> 5, lhl = lane & 31, qloc = lhl >> 4, sub = lhl & 15;
  int d = blockIdx.x * 8 + wv * 2 + h;
  int dc = d < N ? d : N - 1;

  // issue latency-critical loads before LDS staging
  int cnt = cursor[dc * CSTR]; if (cnt > CAP) cnt = CAP;
  uint2 iv = ((const uint2*)(AGG + (size_t)dc * HID))[sub];
  const int* evr = ev + dc * CAP;
  float wreg = rel_weight(evr, cnt, lhl, h);

  for (int i = tid; i < HID * OUT_DIM; i += 256) sWl[i] = Wl[i];
  if (tid < OUT_DIM) sbl[tid] = bl[tid];
  __syncthreads();

  float a0 = 0.f, a1 = 0.f, a2 = 0.f, a3 = 0.f;
  if (qloc == 0) {
    a0 = bflo(iv.x); a1 = bfhi(iv.x); a2 = bflo(iv.y); a3 = bfhi(iv.y);
  }
  agg_half2((const uint2*)H, evr, cnt, qloc, sub, wreg, h, a0, a1, a2, a3);
  if (qloc == 0) {
    float4 v;
    v.x = fmaxf(a0, 0.f); v.y = fmaxf(a1, 0.f);
    v.z = fmaxf(a2, 0.f); v.w = fmaxf(a3, 0.f);
    *(float4*)(&sh[wv * 2 + h][4 * sub]) = v;
  }
  __syncthreads();

  // each wave finishes its 2 dsts sequentially
  #pragma unroll
  for (int ii = 0; ii < 2; ++ii) {
    int dd = blockIdx.x * 8 + wv * 2 + ii;
    const float* row = sh[wv * 2 + ii];
    float logit = -__builtin_inff();
    if (lane < OUT_DIM) {
      float t = sbl[lane];
      #pragma unroll 8
      for (int k = 0; k < HID; ++k) t += row[k] * sWl[k * OUT_DIM + lane];
      logit = t;
    }
    float m = logit;
    #pragma unroll
    for (int o = 32; o > 0; o >>= 1) m = fmaxf(m, __shfl_xor(m, o, 64));
    float ex = (lane < OUT_DIM) ? expf(logit - m) : 0.f;
    float s = ex;
    #pragma unroll
    for (int o = 32; o > 0; o >>= 1) s += __shfl_xor(s, o, 64);
    if (dd < N && lane < OUT_DIM)
      out[(size_t)dd * OUT_DIM + lane] = logit - m - logf(s);
  }
}

// ---- launch ----------------------------------------------------------------
extern "C" void kernel_launch(void* const* d_in, const int* in_sizes, int n_in,
                              void* d_out, int out_size, void* d_ws, size_t ws_size,
                              hipStream_t stream) {
  const float* x     = (const float*)d_in[0];
  const int*   eidx  = (const int*)d_in[1];
  const int*   etype = (const int*)d_in[2];
  const float* W1    = (const float*)d_in[3];
  const float* root1 = (const float*)d_in[4];
  const float* b1    = (const float*)d_in[5];
  const float* W2    = (const float*)d_in[6];
  const float* root2 = (const float*)d_in[7];
  const float* b2    = (const float*)d_in[8];
  const float* Wl    = (const float*)d_in[9];
  const float* bl    = (const float*)d_in[10];

  int N = in_sizes[0] / IN_DIM;   // 50000
  int E = in_sizes[2];            // 800000
  const int* srcp = eidx;
  const int* dstp = eidx + E;

  char* ws = (char*)d_ws;
  size_t off = 0;
  auto alloc = [&](size_t bytes) -> char* {
    char* p = ws + off;
    off += (bytes + 255) & ~(size_t)255;
    return p;
  };
  short* Bt1    = (short*)alloc((size_t)NCOLS * IN_DIM * 2);
  short* Bt2    = (short*)alloc((size_t)NCOLS * HID * 2);
  int*   cursor = (int*)alloc((size_t)N * CSTR * 4);           // 3.2 MB padded
  int*   ev     = (int*)alloc((size_t)N * CAP * 4);            // 12.8 MB
  short* H1     = (short*)alloc((size_t)N * NREL * HID * 2);   // 51.2 MB bf16
  short* H2     = (short*)alloc((size_t)N * NREL * HID * 2);   // 51.2 MB bf16
  unsigned short* AGG1 = (unsigned short*)alloc((size_t)N * HID * 2);
  unsigned short* AGG2 = (unsigned short*)alloc((size_t)N * HID * 2);

  const int PB1 = (NCOLS * IN_DIM + 255) / 256;   // 288
  const int PB2 = (NCOLS * HID + 255) / 256;      // 144
  int nzero4 = (N * CSTR) / 4;                    // int4 count for cursor zero
  int ZB = (nzero4 + 255) / 256;                  // 782
  pack_bt<<<PB1 + PB2 + ZB, 256, 0, stream>>>(W1, root1, Bt1, W2, root2, Bt2,
                                              cursor, nzero4);

  int GB = (N + 63) / 64;           // 782 gemm blocks
  int SB = (E + 1023) / 1024;       // 782 scatter blocks (4 edges/thread)
  gemm1_scatter<<<GB + SB, 256, 0, stream>>>(x, Bt1, b1, H1, AGG1, N, GB,
                                             srcp, dstp, etype, cursor, ev, E);

  csr_agg<<<(N + 7) / 8, 256, 0, stream>>>(H1, cursor, ev, AGG1, N);

  gemm2_mfma<<<GB, 256, 0, stream>>>(AGG1, Bt2, b2, H2, AGG2, N);

  csr_agg_final<<<(N + 7) / 8, 256, 0, stream>>>(H2, cursor, ev, AGG2,
                                                 Wl, bl, (float*)d_out, N);
}

// Round 2
// 217.100 us; speedup vs baseline: 1.1468x; 1.1468x over previous
//
#include <hip/hip_runtime.h>
#include <hip/hip_bf16.h>
#include <cmath>

// R2: revert gemm_dev + scatter to R0 structure (4 blocks/CU, 1 edge/thread);
//     keep R1 wins: no finalize_ev (ballot-histogram weights in agg),
//     cursor-zeroing folded into pack_bt.

#define IN_DIM 128
#define HID 64
#define OUT_DIM 40
#define NREL 8
#define NCOLS 576   // 8*64 (relations) + 64 (root)
#define CAP 64      // max in-degree bucket capacity
#define CSTR 16     // cursor stride (ints) = one 64B line per dst

typedef __attribute__((ext_vector_type(8))) short short8;
typedef __attribute__((ext_vector_type(4))) short short4v;
typedef __attribute__((ext_vector_type(4))) float floatx4;
typedef __attribute__((ext_vector_type(2))) float f32x2;

static __device__ __forceinline__ short f2bf(float f) {
  __hip_bfloat16 h = __float2bfloat16(f);
  return __builtin_bit_cast(short, h);
}
static __device__ __forceinline__ float bflo(unsigned int u) {
  return __int_as_float(u << 16);
}
static __device__ __forceinline__ float bfhi(unsigned int u) {
  return __int_as_float(u & 0xffff0000u);
}
static __device__ __forceinline__ unsigned int packbf(float x, float y) {
  unsigned int lo = (unsigned short)f2bf(x);
  unsigned int hi = (unsigned short)f2bf(y);
  return lo | (hi << 16);
}

// ---- pack Bt1, Bt2 + zero cursor (memset folded in) ------------------------
__global__ void pack_bt(const float* __restrict__ W1, const float* __restrict__ root1,
                        short* __restrict__ Bt1,
                        const float* __restrict__ W2, const float* __restrict__ root2,
                        short* __restrict__ Bt2,
                        int* __restrict__ cursor, int nzero4) {
  const int PB1 = (NCOLS * IN_DIM + 255) / 256;   // 288
  const int PB2 = (NCOLS * HID + 255) / 256;      // 144
  int b = blockIdx.x;
  if (b < PB1) {
    int i = b * 256 + threadIdx.x;
    if (i >= NCOLS * IN_DIM) return;
    int c = i / IN_DIM, k = i % IN_DIM;
    float v = (c < NREL * HID)
      ? W1[((size_t)(c >> 6) * IN_DIM + k) * HID + (c & 63)]
      : root1[(size_t)k * HID + (c - NREL * HID)];
    Bt1[i] = f2bf(v);
  } else if (b < PB1 + PB2) {
    int i = (b - PB1) * 256 + threadIdx.x;
    if (i >= NCOLS * HID) return;
    int c = i / HID, k = i % HID;
    float v = (c < NREL * HID)
      ? W2[((size_t)(c >> 6) * HID + k) * HID + (c & 63)]
      : root2[(size_t)k * HID + (c - NREL * HID)];
    Bt2[i] = f2bf(v);
  } else {
    int i = (b - PB1 - PB2) * 256 + threadIdx.x;
    if (i < nzero4) {
      int4 z; z.x = 0; z.y = 0; z.z = 0; z.w = 0;
      ((int4*)cursor)[i] = z;
    }
  }
}

// ---- shared MFMA GEMM body: C[64 x 576] = act(A tile) @ Bt^T ---------------
// 64-col B tiles (9), 34.8 KB LDS, 4 blocks/CU.
// AMODE 0: A fp32, no relu.  AMODE 1: A bf16, relu.
// cols 0..511 -> H (bf16); cols 512..575 -> AGG (bf16, +bias)
template<int K, int AMODE>
__device__ __forceinline__ void gemm_dev(
    short* As, short* Bs,
    const void* __restrict__ Aptr, const short* __restrict__ Bt,
    const float* __restrict__ bias, short* __restrict__ H,
    unsigned short* __restrict__ AGG, int M, int row0)
{
  constexpr int AST = K + 8;
  int tid = threadIdx.x;
  int wv = tid >> 6, lane = tid & 63;
  int lm = lane & 15, quad = lane >> 4;

  if (AMODE == 0) {
    const float* A = (const float*)Aptr;
    constexpr int CH = K / 4;
    for (int i = tid; i < 64 * CH; i += 256) {
      int r = i / CH, kq = i % CH;
      int gr = row0 + r; if (gr >= M) gr = M - 1;
      float4 v = *(const float4*)(A + (unsigned)(gr * K + kq * 4));
      short4v s;
      s.x = f2bf(v.x); s.y = f2bf(v.y); s.z = f2bf(v.z); s.w = f2bf(v.w);
      *(short4v*)(As + r * AST + kq * 4) = s;
    }
  } else {
    const short* A = (const short*)Aptr;
    constexpr int CH = K / 8;
    for (int i = tid; i < 64 * CH; i += 256) {
      int r = i / CH, ko = i % CH;
      int gr = row0 + r; if (gr >= M) gr = M - 1;
      short8 v = *(const short8*)(A + (unsigned)(gr * K + ko * 8));
      #pragma unroll
      for (int j = 0; j < 8; ++j)
        if ((unsigned short)v[j] & 0x8000u) v[j] = 0;   // bf16 relu
      *(short8*)(As + r * AST + ko * 8) = v;
    }
  }

  const short* ap = As + (16 * wv + lm) * AST + quad * 8;

  for (int cy = 0; cy < 9; ++cy) {
    constexpr int CB = K / 8;
    for (int i = tid; i < 64 * CB; i += 256) {
      int n = i / CB, ko = i % CB;
      short8 v = *(const short8*)(Bt + (unsigned)((cy * 64 + n) * K + ko * 8));
      *(short8*)(Bs + n * AST + ko * 8) = v;
    }
    __syncthreads();

    floatx4 acc[4] = {{0,0,0,0},{0,0,0,0},{0,0,0,0},{0,0,0,0}};
    #pragma unroll
    for (int ks = 0; ks < K / 32; ++ks) {
      short8 a = *(const short8*)(ap + ks * 32);
      #pragma unroll
      for (int nb = 0; nb < 4; ++nb) {
        short8 b = *(const short8*)(Bs + (nb * 16 + lm) * AST + ks * 32 + quad * 8);
        acc[nb] = __builtin_amdgcn_mfma_f32_16x16x32_bf16(a, b, acc[nb], 0, 0, 0);
      }
    }
    __syncthreads();

    int mbase = row0 + 16 * wv + quad * 4;
    if (cy < 8) {
      #pragma unroll
      for (int nb = 0; nb < 4; ++nb) {
        int col = cy * 64 + nb * 16 + lm;
        #pragma unroll
        for (int r = 0; r < 4; ++r) {
          int mg = mbase + r;
          if (mg < M) H[(unsigned)mg * (NREL * HID) + col] = f2bf(acc[nb][r]);
        }
      }
    } else {
      #pragma unroll
      for (int nb = 0; nb < 4; ++nb) {
        int col = nb * 16 + lm;
        float bv = bias[col];
        #pragma unroll
        for (int r = 0; r < 4; ++r) {
          int mg = mbase + r;
          if (mg < M)
            AGG[(unsigned)mg * HID + col] = (unsigned short)f2bf(acc[nb][r] + bv);
        }
      }
    }
  }
}

// ---- fused: gemm layer-1 (blocks < GB) + bucket scatter (blocks >= GB) -----
__global__ __launch_bounds__(256, 4) void gemm1_scatter(
    const float* __restrict__ A, const short* __restrict__ Bt,
    const float* __restrict__ bias, short* __restrict__ H,
    unsigned short* __restrict__ AGG, int M, int GB,
    const int* __restrict__ src, const int* __restrict__ dst,
    const int* __restrict__ et,
    int* __restrict__ cursor, int* __restrict__ ev, int E)
{
  constexpr int AST = IN_DIM + 8;
  __shared__ short As[64 * AST];
  __shared__ short Bs[64 * AST];
  if ((int)blockIdx.x < GB) {
    gemm_dev<IN_DIM, 0>(As, Bs, A, Bt, bias, H, AGG, M, blockIdx.x * 64);
  } else {
    int e = (blockIdx.x - GB) * 256 + threadIdx.x;
    if (e >= E) return;
    int d = dst[e];
    int pos = atomicAdd(&cursor[d * CSTR], 1);
    if (pos < CAP)
      __builtin_nontemporal_store((src[e] << 3) | et[e], &ev[d * CAP + pos]);
  }
}

// ---- gemm layer 2 (bf16 A with relu) ---------------------------------------
__global__ __launch_bounds__(256, 4) void gemm2_mfma(
    const unsigned short* __restrict__ A, const short* __restrict__ Bt,
    const float* __restrict__ bias, short* __restrict__ H,
    unsigned short* __restrict__ AGG, int M)
{
  constexpr int AST = HID + 8;
  __shared__ short As[64 * AST];
  __shared__ short Bs[64 * AST];
  gemm_dev<HID, 1>(As, Bs, A, Bt, bias, H, AGG, M, blockIdx.x * 64);
}

// ---- fast aggregation core: HALF-WAVE per dst, raw ev ----------------------
// Entry v (raw) = (src<<3)|rel = H row index. wreg: lane (h*32+r) carries the
// weight 1/deg(dst,r) (replicated at lhl&7==r). Slots >= cnt masked.
static __device__ __forceinline__ void agg_half2(
    const uint2* __restrict__ Hu2, const int* __restrict__ evrow,
    int cnt, int qloc, int sub, float wreg, int h,
    float& a0, float& a1, float& a2, float& a3)
{
  int npass = (cnt + 15) >> 4;
  f32x2 A01 = {a0, a1}, A23 = {a2, a3};
  for (int P = 0; P < npass; ++P) {
    const int4* pp = (const int4*)(evrow + P * 16 + qloc * 8);
    int4 v0 = pp[0], v1 = pp[1];
    int vv[8] = {v0.x, v0.y, v0.z, v0.w, v1.x, v1.y, v1.z, v1.w};
    int sb = P * 16 + qloc * 8;
    uint2 hv[8];
    float ww[8];
    #pragma unroll
    for (int i = 0; i < 8; ++i) {
      bool ok = (sb + i) < cnt;
      int v = ok ? vv[i] : 0;            // clamp garbage padding slots
      hv[i] = Hu2[(unsigned)v * 16u + (unsigned)sub];
      float w = __shfl(wreg, h * 32 + (v & 7), 64);
      ww[i] = ok ? w : 0.f;
    }
    #pragma unroll
    for (int i = 0; i < 8; ++i) {
      f32x2 w2 = {ww[i], ww[i]};
      f32x2 h01 = {bflo(hv[i].x), bfhi(hv[i].x)};
      f32x2 h23 = {bflo(hv[i].y), bfhi(hv[i].y)};
      A01 += h01 * w2;
      A23 += h23 * w2;
    }
  }
  a0 = A01.x; a1 = A01.y; a2 = A23.x; a3 = A23.y;
  a0 += __shfl_xor(a0, 16, 64);
  a1 += __shfl_xor(a1, 16, 64);
  a2 += __shfl_xor(a2, 16, 64);
  a3 += __shfl_xor(a3, 16, 64);
}

// ballot histogram: per-lane weight 1/deg(dst, lhl&7) for this half's dst
static __device__ __forceinline__ float rel_weight(
    const int* __restrict__ evr, int cnt, int lhl, int h)
{
  int e0 = evr[lhl], e1 = evr[lhl + 32];
  bool v0 = lhl < cnt, v1 = (lhl + 32) < cnt;
  int r0 = e0 & 7, r1 = e1 & 7;
  unsigned long long hm = 0xffffffffull << (h * 32);
  int myrel = lhl & 7;
  int c = 0;
  #pragma unroll
  for (int r = 0; r < 8; ++r) {
    unsigned long long m0 = __ballot(v0 && (r0 == r));
    unsigned long long m1 = __ballot(v1 && (r1 == r));
    int cr = __popcll(m0 & hm) + __popcll(m1 & hm);
    if (myrel == r) c = cr;
  }
  return (c > 0) ? (1.0f / (float)c) : 0.0f;
}

// ---- layer-1 aggregation: 2 dsts per wave, AGG(bf16) += mean-messages ------
__global__ __launch_bounds__(256) void csr_agg(
    const short* __restrict__ H, const int* __restrict__ cursor,
    const int* __restrict__ ev, unsigned short* __restrict__ AGG, int N)
{
  int tid = threadIdx.x;
  int wv = tid >> 6, lane = tid & 63;
  int h = lane >> 5, lhl = lane & 31, qloc = lhl >> 4, sub = lhl & 15;
  int d = blockIdx.x * 8 + wv * 2 + h;
  int dc = d < N ? d : N - 1;

  int cnt = cursor[dc * CSTR]; if (cnt > CAP) cnt = CAP;
  const int* evr = ev + dc * CAP;
  float wreg = rel_weight(evr, cnt, lhl, h);

  float a0 = 0.f, a1 = 0.f, a2 = 0.f, a3 = 0.f;
  uint2* aggrow = (uint2*)(AGG + (size_t)dc * HID);
  if (qloc == 0) {
    uint2 iv = aggrow[sub];
    a0 = bflo(iv.x); a1 = bfhi(iv.x); a2 = bflo(iv.y); a3 = bfhi(iv.y);
  }
  agg_half2((const uint2*)H, evr, cnt, qloc, sub, wreg, h, a0, a1, a2, a3);
  if (d < N && qloc == 0) {
    uint2 ov;
    ov.x = packbf(a0, a1);
    ov.y = packbf(a2, a3);
    aggrow[sub] = ov;
  }
}

// ---- layer-2 aggregation (2 dsts/wave) + relu -> @Wl+bl -> log_softmax -----
__global__ __launch_bounds__(256) void csr_agg_final(
    const short* __restrict__ H, const int* __restrict__ cursor,
    const int* __restrict__ ev, const unsigned short* __restrict__ AGG,
    const float* __restrict__ Wl, const float* __restrict__ bl,
    float* __restrict__ out, int N)
{
  __shared__ float sWl[HID * OUT_DIM];
  __shared__ float sbl[OUT_DIM];
  __shared__ float sh[8][HID];
  int tid = threadIdx.x;
  int wv = tid >> 6, lane = tid & 63;
  int h = lane >> 5, lhl = lane & 31, qloc = lhl >> 4, sub = lhl & 15;
  int d = blockIdx.x * 8 + wv * 2 + h;
  int dc = d < N ? d : N - 1;

  // issue latency-critical loads before LDS staging
  int cnt = cursor[dc * CSTR]; if (cnt > CAP) cnt = CAP;
  uint2 iv = ((const uint2*)(AGG + (size_t)dc * HID))[sub];
  const int* evr = ev + dc * CAP;
  float wreg = rel_weight(evr, cnt, lhl, h);

  for (int i = tid; i < HID * OUT_DIM; i += 256) sWl[i] = Wl[i];
  if (tid < OUT_DIM) sbl[tid] = bl[tid];
  __syncthreads();

  float a0 = 0.f, a1 = 0.f, a2 = 0.f, a3 = 0.f;
  if (qloc == 0) {
    a0 = bflo(iv.x); a1 = bfhi(iv.x); a2 = bflo(iv.y); a3 = bfhi(iv.y);
  }
  agg_half2((const uint2*)H, evr, cnt, qloc, sub, wreg, h, a0, a1, a2, a3);
  if (qloc == 0) {
    float4 v;
    v.x = fmaxf(a0, 0.f); v.y = fmaxf(a1, 0.f);
    v.z = fmaxf(a2, 0.f); v.w = fmaxf(a3, 0.f);
    *(float4*)(&sh[wv * 2 + h][4 * sub]) = v;
  }
  __syncthreads();

  // each wave finishes its 2 dsts sequentially
  #pragma unroll
  for (int ii = 0; ii < 2; ++ii) {
    int dd = blockIdx.x * 8 + wv * 2 + ii;
    const float* row = sh[wv * 2 + ii];
    float logit = -__builtin_inff();
    if (lane < OUT_DIM) {
      float t = sbl[lane];
      #pragma unroll 8
      for (int k = 0; k < HID; ++k) t += row[k] * sWl[k * OUT_DIM + lane];
      logit = t;
    }
    float m = logit;
    #pragma unroll
    for (int o = 32; o > 0; o >>= 1) m = fmaxf(m, __shfl_xor(m, o, 64));
    float ex = (lane < OUT_DIM) ? expf(logit - m) : 0.f;
    float s = ex;
    #pragma unroll
    for (int o = 32; o > 0; o >>= 1) s += __shfl_xor(s, o, 64);
    if (dd < N && lane < OUT_DIM)
      out[(size_t)dd * OUT_DIM + lane] = logit - m - logf(s);
  }
}

// ---- launch ----------------------------------------------------------------
extern "C" void kernel_launch(void* const* d_in, const int* in_sizes, int n_in,
                              void* d_out, int out_size, void* d_ws, size_t ws_size,
                              hipStream_t stream) {
  const float* x     = (const float*)d_in[0];
  const int*   eidx  = (const int*)d_in[1];
  const int*   etype = (const int*)d_in[2];
  const float* W1    = (const float*)d_in[3];
  const float* root1 = (const float*)d_in[4];
  const float* b1    = (const float*)d_in[5];
  const float* W2    = (const float*)d_in[6];
  const float* root2 = (const float*)d_in[7];
  const float* b2    = (const float*)d_in[8];
  const float* Wl    = (const float*)d_in[9];
  const float* bl    = (const float*)d_in[10];

  int N = in_sizes[0] / IN_DIM;   // 50000
  int E = in_sizes[2];            // 800000
  const int* srcp = eidx;
  const int* dstp = eidx + E;

  char* ws = (char*)d_ws;
  size_t off = 0;
  auto alloc = [&](size_t bytes) -> char* {
    char* p = ws + off;
    off += (bytes + 255) & ~(size_t)255;
    return p;
  };
  short* Bt1    = (short*)alloc((size_t)NCOLS * IN_DIM * 2);
  short* Bt2    = (short*)alloc((size_t)NCOLS * HID * 2);
  int*   cursor = (int*)alloc((size_t)N * CSTR * 4);           // 3.2 MB padded
  int*   ev     = (int*)alloc((size_t)N * CAP * 4);            // 12.8 MB
  short* H1     = (short*)alloc((size_t)N * NREL * HID * 2);   // 51.2 MB bf16
  short* H2     = (short*)alloc((size_t)N * NREL * HID * 2);   // 51.2 MB bf16
  unsigned short* AGG1 = (unsigned short*)alloc((size_t)N * HID * 2);
  unsigned short* AGG2 = (unsigned short*)alloc((size_t)N * HID * 2);

  const int PB1 = (NCOLS * IN_DIM + 255) / 256;   // 288
  const int PB2 = (NCOLS * HID + 255) / 256;      // 144
  int nzero4 = (N * CSTR) / 4;                    // int4 count for cursor zero
  int ZB = (nzero4 + 255) / 256;                  // 782
  pack_bt<<<PB1 + PB2 + ZB, 256, 0, stream>>>(W1, root1, Bt1, W2, root2, Bt2,
                                              cursor, nzero4);

  int GB = (N + 63) / 64;          // 782 gemm blocks
  int SB = (E + 255) / 256;        // 3125 scatter blocks
  gemm1_scatter<<<GB + SB, 256, 0, stream>>>(x, Bt1, b1, H1, AGG1, N, GB,
                                             srcp, dstp, etype, cursor, ev, E);

  csr_agg<<<(N + 7) / 8, 256, 0, stream>>>(H1, cursor, ev, AGG1, N);

  gemm2_mfma<<<GB, 256, 0, stream>>>(AGG1, Bt2, b2, H2, AGG2, N);

  csr_agg_final<<<(N + 7) / 8, 256, 0, stream>>>(H2, cursor, ev, AGG2,
                                                 Wl, bl, (float*)d_out, N);
}